// Round 10
// baseline (812.230 us; speedup 1.0000x reference)
//
#include <hip/hip_runtime.h>
#include <hip/hip_bf16.h>

#define T_TOK 2048
#define H_DIM 2048
#define E_NUM 32
#define I_DIM 768
#define TOPK  4
#define S4    (T_TOK * TOPK)          // 8192 slots

typedef __attribute__((ext_vector_type(8))) short bf16x8;
typedef __attribute__((ext_vector_type(4))) float f32x4;

__device__ __forceinline__ unsigned pk2(float a, float b) {
    __hip_bfloat16 ha = __float2bfloat16(a);
    __hip_bfloat16 hb = __float2bfloat16(b);
    unsigned short ua = *(unsigned short*)&ha;
    unsigned short ub = *(unsigned short*)&hb;
    return (unsigned)ua | ((unsigned)ub << 16);
}

__device__ __forceinline__ void gld16(const void* g, void* l) {
    __builtin_amdgcn_global_load_lds(
        (const __attribute__((address_space(1))) void*)g,
        (__attribute__((address_space(3))) void*)l, 16, 0, 0);
}

// expert-from-blockid: bid%8 selects XCD (round-robin dispatch), so experts with
// e%8 == bid%8 pin to one XCD -> their activation panel stays in that L2.
__device__ __forceinline__ int eswz(int bid) {
    return (bid & 7) | (((bid >> 3) & 3) << 3);
}

// ---------------- fast zero of out ----------------
__global__ __launch_bounds__(256) void zero_kernel(uint4* __restrict__ p, int n16)
{
    int i = blockIdx.x * 256 + threadIdx.x;
    if (i < n16) p[i] = (uint4){0u, 0u, 0u, 0u};
}

// ---------------- Router ----------------
__global__ __launch_bounds__(64) void router_kernel(
    const float* __restrict__ x, const float* __restrict__ gate_w,
    float* __restrict__ logits_out, int* __restrict__ cnt,
    int* __restrict__ tok_list, float* __restrict__ tok_w)
{
    const int t = blockIdx.x;
    const int lane = threadIdx.x;
    __shared__ float xs[H_DIM];
    const float4* __restrict__ xv = (const float4*)(x + (size_t)t * H_DIM);
    float4* xsv = (float4*)xs;
#pragma unroll
    for (int i = 0; i < H_DIM / 4 / 64; ++i) xsv[lane + i * 64] = xv[lane + i * 64];
    __syncthreads();

    const int e = lane & 31;
    const int half = lane >> 5;
    const float4* __restrict__ wv = (const float4*)(gate_w + (size_t)e * H_DIM) + half * (H_DIM / 8);
    const float4* __restrict__ xh = ((const float4*)xs) + half * (H_DIM / 8);
    float acc = 0.f;
#pragma unroll 4
    for (int i = 0; i < H_DIM / 8; ++i) {
        float4 w4 = wv[i], x4 = xh[i];
        acc += w4.x * x4.x + w4.y * x4.y + w4.z * x4.z + w4.w * x4.w;
    }
    acc += __shfl_xor(acc, 32, 64);
    if (lane < 32) logits_out[(size_t)t * E_NUM + e] = acc;

    float v = acc;
    float topv[TOPK]; int topi[TOPK];
#pragma unroll
    for (int r = 0; r < TOPK; ++r) {
        float bv = v; int bi = e;
#pragma unroll
        for (int off = 16; off >= 1; off >>= 1) {
            float ov = __shfl_xor(bv, off, 32);
            int   oi = __shfl_xor(bi, off, 32);
            if (ov > bv || (ov == bv && oi < bi)) { bv = ov; bi = oi; }
        }
        topv[r] = bv; topi[r] = bi;
        if (e == bi) v = -1e30f;
    }
    if (lane == 0) {
        float w[TOPK]; float s = 0.f;
#pragma unroll
        for (int r = 0; r < TOPK; ++r) { w[r] = expf(topv[r] - topv[0]); s += w[r]; }
        float inv = 1.f / s;
#pragma unroll
        for (int r = 0; r < TOPK; ++r) {
            int pos = atomicAdd(&cnt[topi[r]], 1);
            tok_list[topi[r] * T_TOK + pos] = t;
            tok_w  [topi[r] * T_TOK + pos] = w[r] * inv;
        }
    }
}

__global__ void scan_kernel(const int* __restrict__ cnt, int* __restrict__ slot_base)
{
    if (threadIdx.x == 0) {
        int s = 0;
        for (int e = 0; e < E_NUM; ++e) { slot_base[e] = s; s += cnt[e]; }
        slot_base[E_NUM] = s;
    }
}

// ------- Gather tokens per expert, convert x -> bf16 in K-PANEL layout -------
// xg_t[kc][slot][8]; 1D grid, expert pinned to XCD e%8.
__global__ __launch_bounds__(256) void gather_kernel(
    const float* __restrict__ x, const int* __restrict__ cnt,
    const int* __restrict__ slot_base, const int* __restrict__ tok_list,
    unsigned short* __restrict__ xg_t)
{
    const int bid = blockIdx.x;
    const int e = eswz(bid);
    const int count = cnt[e];
    const int m0 = (bid >> 5) * 8;
    if (m0 >= count) return;
    const int s8   = threadIdx.x >> 5;
    const int kc31 = threadIdx.x & 31;
    const int m = m0 + s8;
    if (m >= count) return;
    const int tok  = tok_list[e * T_TOK + m];
    const int slot = slot_base[e] + m;
    const float* __restrict__ src = x + (size_t)tok * H_DIM;
#pragma unroll
    for (int kcq = 0; kcq < 8; ++kcq) {
        const int kc = kcq * 32 + kc31;
        float4 a = *(const float4*)(src + kc * 8);
        float4 b = *(const float4*)(src + kc * 8 + 4);
        uint4 o;
        o.x = pk2(a.x, a.y); o.y = pk2(a.z, a.w);
        o.z = pk2(b.x, b.y); o.w = pk2(b.z, b.w);
        *(uint4*)(xg_t + ((size_t)kc * S4 + slot) * 8) = o;
    }
}

// ---------------- gate_up MFMA + silu + weight-scale -> h_t (panel bf16) -----
// tile 256(M) x 32(g)+32(u), BK=32, 8 waves, dbuf. LDS exactly 40KB -> 4 blocks/CU.
// 1D grid 6144 = 32e x 24nt x 8mt; expert pinned to XCD e%8 for A L2 locality.
#define GU_NT (H_DIM / 32)
__global__ __launch_bounds__(512, 8) void gateup_mfma(
    const unsigned short* __restrict__ xg_t, const float* __restrict__ gup_w,
    const int* __restrict__ cnt, const int* __restrict__ slot_base,
    const float* __restrict__ tok_w, unsigned short* __restrict__ h_t)
{
    const int bid = blockIdx.x;
    const int e    = eswz(bid);
    const int rest = bid >> 5;
    const int nt   = rest % 24;
    const int mt   = rest / 24;
    const int count = cnt[e];
    if (mt * 256 >= count) return;
    const int tid  = threadIdx.x;
    const int lane = tid & 63;
    const int w    = tid >> 6;
    const int base = slot_base[e];
    const int l16  = lane & 15, lg = lane >> 4;

    __shared__ unsigned short As[2][4 * 256 * 8];   // 32 KB  [kc][m][8]
    __shared__ unsigned short Bg[2][4 * 32 * 8];    //  4 KB  [kc][n][8]
    __shared__ unsigned short Bu[2][4 * 32 * 8];    //  4 KB   -> total 40960 B

    // A staging from panels: wave -> kc = w>>1, two 64-row bands (coalesced)
    const int kc = w >> 1;
    const int q0 = (w & 1) * 2;
    int r0 = mt * 256 + q0 * 64 + lane;       if (r0 >= count) r0 = count - 1;
    int r1 = mt * 256 + (q0 + 1) * 64 + lane; if (r1 >= count) r1 = count - 1;
    const unsigned short* ag0 = xg_t + (size_t)kc * (S4 * 8) + (size_t)(base + r0) * 8;
    const unsigned short* ag1 = xg_t + (size_t)kc * (S4 * 8) + (size_t)(base + r1) * 8;
    const int al0 = (kc * 256 + q0 * 64) * 8;
    const int al1 = (kc * 256 + (q0 + 1) * 64) * 8;
    const size_t astep = (size_t)4 * S4 * 8;

    // B staging: threads 0..255; bhalf=gate/up, k-pair kb, 4 cols n4 (float4)
    const bool bstage = tid < 256;
    const int bhalf = (tid >> 7) & 1;
    const int t7    = tid & 127;
    const int kb    = (t7 >> 3) * 2;
    const int n4    = (t7 & 7) * 4;
    const int kcb   = kb >> 3;
    const int k8    = kb & 7;
    const float* __restrict__ bsrc =
        gup_w + ((size_t)e * H_DIM + kb) * (2 * I_DIM) + (size_t)bhalf * I_DIM + nt * 32 + n4;

    const int aoff = (lg * 256 + w * 32 + l16) * 8;
    const int boff = (lg * 32 + l16) * 8;

    f32x4 accg[2][2], accu[2][2];
#pragma unroll
    for (int i = 0; i < 2; ++i)
#pragma unroll
        for (int f = 0; f < 2; ++f) { accg[i][f] = {0.f,0.f,0.f,0.f}; accu[i][f] = {0.f,0.f,0.f,0.f}; }

    float4 pr0, pr1;

    gld16(ag0, &As[0][al0]);
    gld16(ag1, &As[0][al1]);
    if (bstage) {
        pr0 = *(const float4*)bsrc;
        pr1 = *(const float4*)(bsrc + 2 * I_DIM);
        unsigned short* bw = bhalf ? &Bu[0][0] : &Bg[0][0];
        float p0[4] = {pr0.x, pr0.y, pr0.z, pr0.w};
        float p1[4] = {pr1.x, pr1.y, pr1.z, pr1.w};
#pragma unroll
        for (int j = 0; j < 4; ++j)
            *(unsigned*)&bw[((kcb * 32 + n4 + j) * 8) + k8] = pk2(p0[j], p1[j]);
    }

    for (int ks = 0; ks < GU_NT; ++ks) {
        const int cur = ks & 1;
        __syncthreads();
        if (ks + 1 < GU_NT) {
            gld16(ag0 + (size_t)(ks + 1) * astep, &As[cur ^ 1][al0]);
            gld16(ag1 + (size_t)(ks + 1) * astep, &As[cur ^ 1][al1]);
            if (bstage) {
                const float* bs_ = bsrc + (size_t)(ks + 1) * 32 * (2 * I_DIM);
                pr0 = *(const float4*)bs_;
                pr1 = *(const float4*)(bs_ + 2 * I_DIM);
            }
        }
        {
            const unsigned short* af_ = &As[cur][aoff];
            const unsigned short* bg_ = &Bg[cur][boff];
            const unsigned short* bu_ = &Bu[cur][boff];
            bf16x8 vg0 = *(const bf16x8*)(bg_);
            bf16x8 vg1 = *(const bf16x8*)(bg_ + 128);
            bf16x8 vu0 = *(const bf16x8*)(bu_);
            bf16x8 vu1 = *(const bf16x8*)(bu_ + 128);
#pragma unroll
            for (int i = 0; i < 2; ++i) {
                bf16x8 va = *(const bf16x8*)(af_ + i * 16 * 8);
                accg[i][0] = __builtin_amdgcn_mfma_f32_16x16x32_bf16(va, vg0, accg[i][0], 0, 0, 0);
                accg[i][1] = __builtin_amdgcn_mfma_f32_16x16x32_bf16(va, vg1, accg[i][1], 0, 0, 0);
                accu[i][0] = __builtin_amdgcn_mfma_f32_16x16x32_bf16(va, vu0, accu[i][0], 0, 0, 0);
                accu[i][1] = __builtin_amdgcn_mfma_f32_16x16x32_bf16(va, vu1, accu[i][1], 0, 0, 0);
            }
        }
        if (ks + 1 < GU_NT && bstage) {
            unsigned short* bw = bhalf ? &Bu[cur ^ 1][0] : &Bg[cur ^ 1][0];
            float p0[4] = {pr0.x, pr0.y, pr0.z, pr0.w};
            float p1[4] = {pr1.x, pr1.y, pr1.z, pr1.w};
#pragma unroll
            for (int j = 0; j < 4; ++j)
                *(unsigned*)&bw[((kcb * 32 + n4 + j) * 8) + k8] = pk2(p0[j], p1[j]);
        }
    }

    // epilogue: silu(g)*u*wgt -> h_t panels [ic][slot][8]; wgt loaded from global
#pragma unroll
    for (int i = 0; i < 2; ++i) {
        const int mloc = w * 32 + i * 16 + lg * 4;
#pragma unroll
        for (int r = 0; r < 4; ++r) {
            const int mrow = mt * 256 + mloc + r;
            if (mrow < count) {
                const float wgt = tok_w[e * T_TOK + mrow];
                const size_t slot = (size_t)(base + mrow);
#pragma unroll
                for (int f = 0; f < 2; ++f) {
                    const int col = nt * 32 + f * 16 + l16;
                    float g = accg[i][f][r], u = accu[i][f][r];
                    float sv = g / (1.f + expf(-g));
                    __hip_bfloat16 hb = __float2bfloat16(wgt * u * sv);
                    h_t[((size_t)(col >> 3) * S4 + slot) * 8 + (col & 7)] = *(unsigned short*)&hb;
                }
            }
        }
    }
}

// ---------------- down MFMA -> atomic accumulate into out ----------------
// tile 256(M) x 64(N), BK=32, 8 waves, dbuf. LDS exactly 40KB -> 4 blocks/CU.
// 1D grid 8192 = 32e x 32nt x 8mt; expert pinned to XCD e%8.
#define DN_NT (I_DIM / 32)
__global__ __launch_bounds__(512, 8) void down_mfma(
    const unsigned short* __restrict__ h_t, const float* __restrict__ down_w,
    const int* __restrict__ cnt, const int* __restrict__ slot_base,
    const int* __restrict__ tok_list, float* __restrict__ out)
{
    const int bid = blockIdx.x;
    const int e    = eswz(bid);
    const int rest = bid >> 5;
    const int nt   = rest & 31;
    const int mt   = rest >> 5;
    const int count = cnt[e];
    if (mt * 256 >= count) return;
    const int tid  = threadIdx.x;
    const int lane = tid & 63;
    const int w    = tid >> 6;
    const int base = slot_base[e];
    const int l16  = lane & 15, lg = lane >> 4;

    __shared__ unsigned short As[2][4 * 256 * 8];   // 32 KB
    __shared__ unsigned short Bs[2][4 * 64 * 8];    //  8 KB   -> total 40960 B

    const int kc = w >> 1;
    const int q0 = (w & 1) * 2;
    int r0 = mt * 256 + q0 * 64 + lane;       if (r0 >= count) r0 = count - 1;
    int r1 = mt * 256 + (q0 + 1) * 64 + lane; if (r1 >= count) r1 = count - 1;
    const unsigned short* ag0 = h_t + (size_t)kc * (S4 * 8) + (size_t)(base + r0) * 8;
    const unsigned short* ag1 = h_t + (size_t)kc * (S4 * 8) + (size_t)(base + r1) * 8;
    const int al0 = (kc * 256 + q0 * 64) * 8;
    const int al1 = (kc * 256 + (q0 + 1) * 64) * 8;
    const size_t astep = (size_t)4 * S4 * 8;

    const bool bstage = tid < 256;
    const int t8  = tid & 255;
    const int kb  = (t8 >> 4) * 2;
    const int n4  = (t8 & 15) * 4;
    const int kcb = kb >> 3;
    const int k8  = kb & 7;
    const float* __restrict__ bsrc =
        down_w + ((size_t)e * I_DIM + kb) * H_DIM + nt * 64 + n4;

    const int aoff = (lg * 256 + w * 32 + l16) * 8;
    const int boff = (lg * 64 + l16) * 8;

    f32x4 acc[2][4];
#pragma unroll
    for (int i = 0; i < 2; ++i)
#pragma unroll
        for (int f = 0; f < 4; ++f) acc[i][f] = {0.f,0.f,0.f,0.f};

    float4 pr0, pr1;

    gld16(ag0, &As[0][al0]);
    gld16(ag1, &As[0][al1]);
    if (bstage) {
        pr0 = *(const float4*)bsrc;
        pr1 = *(const float4*)(bsrc + H_DIM);
        float p0[4] = {pr0.x, pr0.y, pr0.z, pr0.w};
        float p1[4] = {pr1.x, pr1.y, pr1.z, pr1.w};
#pragma unroll
        for (int j = 0; j < 4; ++j)
            *(unsigned*)&Bs[0][((kcb * 64 + n4 + j) * 8) + k8] = pk2(p0[j], p1[j]);
    }

    for (int ks = 0; ks < DN_NT; ++ks) {
        const int cur = ks & 1;
        __syncthreads();
        if (ks + 1 < DN_NT) {
            gld16(ag0 + (size_t)(ks + 1) * astep, &As[cur ^ 1][al0]);
            gld16(ag1 + (size_t)(ks + 1) * astep, &As[cur ^ 1][al1]);
            if (bstage) {
                const float* bs_ = bsrc + (size_t)(ks + 1) * 32 * H_DIM;
                pr0 = *(const float4*)bs_;
                pr1 = *(const float4*)(bs_ + H_DIM);
            }
        }
        {
            const unsigned short* af_ = &As[cur][aoff];
            const unsigned short* bf_ = &Bs[cur][boff];
            bf16x8 vb0 = *(const bf16x8*)(bf_);
            bf16x8 vb1 = *(const bf16x8*)(bf_ + 128);
            bf16x8 vb2 = *(const bf16x8*)(bf_ + 256);
            bf16x8 vb3 = *(const bf16x8*)(bf_ + 384);
#pragma unroll
            for (int i = 0; i < 2; ++i) {
                bf16x8 va = *(const bf16x8*)(af_ + i * 16 * 8);
                acc[i][0] = __builtin_amdgcn_mfma_f32_16x16x32_bf16(va, vb0, acc[i][0], 0, 0, 0);
                acc[i][1] = __builtin_amdgcn_mfma_f32_16x16x32_bf16(va, vb1, acc[i][1], 0, 0, 0);
                acc[i][2] = __builtin_amdgcn_mfma_f32_16x16x32_bf16(va, vb2, acc[i][2], 0, 0, 0);
                acc[i][3] = __builtin_amdgcn_mfma_f32_16x16x32_bf16(va, vb3, acc[i][3], 0, 0, 0);
            }
        }
        if (ks + 1 < DN_NT && bstage) {
            float p0[4] = {pr0.x, pr0.y, pr0.z, pr0.w};
            float p1[4] = {pr1.x, pr1.y, pr1.z, pr1.w};
#pragma unroll
            for (int j = 0; j < 4; ++j)
                *(unsigned*)&Bs[cur ^ 1][((kcb * 64 + n4 + j) * 8) + k8] = pk2(p0[j], p1[j]);
        }
    }

#pragma unroll
    for (int i = 0; i < 2; ++i) {
        const int mloc = w * 32 + i * 16 + lg * 4;
#pragma unroll
        for (int r = 0; r < 4; ++r) {
            const int mrow = mt * 256 + mloc + r;
            if (mrow < count) {
                const int tok = tok_list[e * T_TOK + mrow];
#pragma unroll
                for (int f = 0; f < 4; ++f) {
                    const int col = nt * 64 + f * 16 + l16;
                    atomicAdd(&out[(size_t)tok * H_DIM + col], acc[i][f][r]);
                }
            }
        }
    }
}

extern "C" void kernel_launch(void* const* d_in, const int* in_sizes, int n_in,
                              void* d_out, int out_size, void* d_ws, size_t ws_size,
                              hipStream_t stream) {
    const float* x      = (const float*)d_in[0];
    const float* gate_w = (const float*)d_in[1];
    const float* gup_w  = (const float*)d_in[2];
    const float* down_w = (const float*)d_in[3];
    float* out    = (float*)d_out;

    char* wsp = (char*)d_ws;
    int*   cnt       = (int*)(wsp);
    int*   slot_base = (int*)(wsp + 256);
    int*   tok_list  = (int*)(wsp + 4096);
    float* tok_w     = (float*)(wsp + 4096 + (size_t)E_NUM * T_TOK * 4);
    unsigned short* xg_t = (unsigned short*)(wsp + (1u << 20));                          // 33.6 MB
    unsigned short* h_t  = (unsigned short*)(wsp + (1u << 20) + (size_t)S4 * H_DIM * 2); // 12.6 MB

    const int n16 = T_TOK * H_DIM / 4;
    zero_kernel<<<(n16 + 255) / 256, 256, 0, stream>>>((uint4*)out, n16);
    hipMemsetAsync(cnt, 0, 256, stream);

    router_kernel<<<T_TOK, 64, 0, stream>>>(x, gate_w, out + (size_t)T_TOK * H_DIM,
                                            cnt, tok_list, tok_w);
    scan_kernel<<<1, 64, 0, stream>>>(cnt, slot_base);
    gather_kernel<<<E_NUM * 256, 256, 0, stream>>>(x, cnt, slot_base, tok_list, xg_t);
    gateup_mfma<<<E_NUM * 24 * 8, 512, 0, stream>>>(
        xg_t, gup_w, cnt, slot_base, tok_w, h_t);
    down_mfma<<<E_NUM * 32 * 8, 512, 0, stream>>>(
        h_t, down_w, cnt, slot_base, tok_list, out);
}

// Round 11
// 467.629 us; speedup vs baseline: 1.7369x; 1.7369x over previous
//
#include <hip/hip_runtime.h>
#include <hip/hip_bf16.h>

#define T_TOK 2048
#define H_DIM 2048
#define E_NUM 32
#define I_DIM 768
#define TOPK  4
#define S4    (T_TOK * TOPK)          // 8192 slots

typedef __attribute__((ext_vector_type(8))) short bf16x8;
typedef __attribute__((ext_vector_type(4))) float f32x4;

__device__ __forceinline__ unsigned pk2(float a, float b) {
    __hip_bfloat16 ha = __float2bfloat16(a);
    __hip_bfloat16 hb = __float2bfloat16(b);
    unsigned short ua = *(unsigned short*)&ha;
    unsigned short ub = *(unsigned short*)&hb;
    return (unsigned)ua | ((unsigned)ub << 16);
}

#define MFMA16(a, b, c) __builtin_amdgcn_mfma_f32_16x16x32_bf16(a, b, c, 0, 0, 0)

// ---------------- fast zero of out ----------------
__global__ __launch_bounds__(256) void zero_kernel(uint4* __restrict__ p, int n16)
{
    int i = blockIdx.x * 256 + threadIdx.x;
    if (i < n16) p[i] = (uint4){0u, 0u, 0u, 0u};
}

// ---------------- Router ----------------
__global__ __launch_bounds__(64) void router_kernel(
    const float* __restrict__ x, const float* __restrict__ gate_w,
    float* __restrict__ logits_out, int* __restrict__ cnt,
    int* __restrict__ tok_list, float* __restrict__ tok_w)
{
    const int t = blockIdx.x;
    const int lane = threadIdx.x;
    __shared__ float xs[H_DIM];
    const float4* __restrict__ xv = (const float4*)(x + (size_t)t * H_DIM);
    float4* xsv = (float4*)xs;
#pragma unroll
    for (int i = 0; i < H_DIM / 4 / 64; ++i) xsv[lane + i * 64] = xv[lane + i * 64];
    __syncthreads();

    const int e = lane & 31;
    const int half = lane >> 5;
    const float4* __restrict__ wv = (const float4*)(gate_w + (size_t)e * H_DIM) + half * (H_DIM / 8);
    const float4* __restrict__ xh = ((const float4*)xs) + half * (H_DIM / 8);
    float acc = 0.f;
#pragma unroll 4
    for (int i = 0; i < H_DIM / 8; ++i) {
        float4 w4 = wv[i], x4 = xh[i];
        acc += w4.x * x4.x + w4.y * x4.y + w4.z * x4.z + w4.w * x4.w;
    }
    acc += __shfl_xor(acc, 32, 64);
    if (lane < 32) logits_out[(size_t)t * E_NUM + e] = acc;

    float v = acc;
    float topv[TOPK]; int topi[TOPK];
#pragma unroll
    for (int r = 0; r < TOPK; ++r) {
        float bv = v; int bi = e;
#pragma unroll
        for (int off = 16; off >= 1; off >>= 1) {
            float ov = __shfl_xor(bv, off, 32);
            int   oi = __shfl_xor(bi, off, 32);
            if (ov > bv || (ov == bv && oi < bi)) { bv = ov; bi = oi; }
        }
        topv[r] = bv; topi[r] = bi;
        if (e == bi) v = -1e30f;
    }
    if (lane == 0) {
        float w[TOPK]; float s = 0.f;
#pragma unroll
        for (int r = 0; r < TOPK; ++r) { w[r] = expf(topv[r] - topv[0]); s += w[r]; }
        float inv = 1.f / s;
#pragma unroll
        for (int r = 0; r < TOPK; ++r) {
            int pos = atomicAdd(&cnt[topi[r]], 1);
            tok_list[topi[r] * T_TOK + pos] = t;
            tok_w  [topi[r] * T_TOK + pos] = w[r] * inv;
        }
    }
}

__global__ void scan_kernel(const int* __restrict__ cnt, int* __restrict__ slot_base)
{
    if (threadIdx.x == 0) {
        int s = 0;
        for (int e = 0; e < E_NUM; ++e) { slot_base[e] = s; s += cnt[e]; }
        slot_base[E_NUM] = s;
    }
}

// ------- Gather tokens per expert, convert x -> bf16 in K-PANEL layout -------
__global__ __launch_bounds__(256) void gather_kernel(
    const float* __restrict__ x, const int* __restrict__ cnt,
    const int* __restrict__ slot_base, const int* __restrict__ tok_list,
    unsigned short* __restrict__ xg_t)
{
    const int e = blockIdx.x;
    const int count = cnt[e];
    const int m0 = blockIdx.y * 8;
    if (m0 >= count) return;
    const int s8   = threadIdx.x >> 5;
    const int kc31 = threadIdx.x & 31;
    const int m = m0 + s8;
    if (m >= count) return;
    const int tok  = tok_list[e * T_TOK + m];
    const int slot = slot_base[e] + m;
    const float* __restrict__ src = x + (size_t)tok * H_DIM;
#pragma unroll
    for (int kcq = 0; kcq < 8; ++kcq) {
        const int kc = kcq * 32 + kc31;
        float4 a = *(const float4*)(src + kc * 8);
        float4 b = *(const float4*)(src + kc * 8 + 4);
        uint4 o;
        o.x = pk2(a.x, a.y); o.y = pk2(a.z, a.w);
        o.z = pk2(b.x, b.y); o.w = pk2(b.z, b.w);
        *(uint4*)(xg_t + ((size_t)kc * S4 + slot) * 8) = o;
    }
}

// ---------------- gate_up MFMA + silu + weight-scale -> h_t (panel bf16) -----
// tile 256(M) x 32(g)+32(u); A reg-direct from panels (no A LDS);
// B staged per 128-K chunk (4 MFMA steps / barrier). grid (32e, 24nt, 8mt).
#define GU_NC (H_DIM / 128)   // 16 chunks
__global__ __launch_bounds__(512, 4) void gateup_mfma(
    const unsigned short* __restrict__ xg_t, const float* __restrict__ gup_w,
    const int* __restrict__ cnt, const int* __restrict__ slot_base,
    const float* __restrict__ tok_w, unsigned short* __restrict__ h_t)
{
    const int e  = blockIdx.x;
    const int nt = blockIdx.y;
    const int mt = blockIdx.z;
    const int count = cnt[e];
    if (mt * 256 >= count) return;
    const int tid  = threadIdx.x;
    const int lane = tid & 63;
    const int w    = tid >> 6;
    const int base = slot_base[e];
    const int l16  = lane & 15, lg = lane >> 4;

    __shared__ unsigned short Bls[2][2][16 * 32 * 8];  // [buf][half][kc16][n32][8] 32KB
    __shared__ float wls[256];                         // 1KB

    if (tid < 256) {
        int m = mt * 256 + tid; if (m >= count) m = count - 1;
        wls[tid] = tok_w[e * T_TOK + m];
    }

    // A fragment granule bases (per-lane, clamped): lane (l16,lg) -> row l16, k-chunk lg
    int m0 = mt * 256 + w * 32 + l16;      if (m0 >= count) m0 = count - 1;
    int m1 = mt * 256 + w * 32 + 16 + l16; if (m1 >= count) m1 = count - 1;
    const unsigned short* a0b = xg_t + (size_t)(base + m0) * 8;
    const unsigned short* a1b = xg_t + (size_t)(base + m1) * 8;

    // B staging ids: bhalf=gate/up, sub picks kcq pair {sub, sub+2}, kb k-pair, n4 cols
    const int bhalf = tid >> 8;
    const int sub   = (tid >> 7) & 1;
    const int t7    = tid & 127;
    const int kb    = (t7 >> 3) * 2;
    const int n4    = (t7 & 7) * 4;
    const int k8    = kb & 7;
    const int kbh   = kb >> 3;
    const float* __restrict__ bbase =
        gup_w + ((size_t)e * H_DIM + kb) * (2 * I_DIM) + (size_t)bhalf * I_DIM + nt * 32 + n4;

    float4 sv0[2], sv1[2];

#define GU_LOAD(C) do { _Pragma("unroll") for (int q2 = 0; q2 < 2; ++q2) { \
        const int q = sub + q2 * 2; \
        const float* s_ = bbase + (size_t)((C) * 128 + q * 32) * (2 * I_DIM); \
        sv0[q2] = *(const float4*)s_; \
        sv1[q2] = *(const float4*)(s_ + 2 * I_DIM); } } while (0)
#define GU_WRITE(BUF) do { _Pragma("unroll") for (int q2 = 0; q2 < 2; ++q2) { \
        const int q = sub + q2 * 2; \
        unsigned short* bw_ = &Bls[BUF][bhalf][((q * 4 + kbh) * 32) * 8]; \
        float p0[4] = {sv0[q2].x, sv0[q2].y, sv0[q2].z, sv0[q2].w}; \
        float p1[4] = {sv1[q2].x, sv1[q2].y, sv1[q2].z, sv1[q2].w}; \
        _Pragma("unroll") for (int j = 0; j < 4; ++j) \
            *(unsigned*)&bw_[(n4 + j) * 8 + k8] = pk2(p0[j], p1[j]); } } while (0)

    f32x4 accg[2][2], accu[2][2];
#pragma unroll
    for (int i = 0; i < 2; ++i)
#pragma unroll
        for (int f = 0; f < 2; ++f) { accg[i][f] = {0.f,0.f,0.f,0.f}; accu[i][f] = {0.f,0.f,0.f,0.f}; }

    GU_LOAD(0);
    GU_WRITE(0);

    for (int c = 0; c < GU_NC; ++c) {
        const int buf = c & 1;
        __syncthreads();                       // publish Bls[buf] for chunk c
        if (c + 1 < GU_NC) GU_LOAD(c + 1);     // issue-early (lands during compute)
#pragma unroll
        for (int s = 0; s < 4; ++s) {
            const size_t aoff = (size_t)(c * 16 + s * 4 + lg) * (S4 * 8);
            bf16x8 a0 = *(const bf16x8*)(a0b + aoff);
            bf16x8 a1 = *(const bf16x8*)(a1b + aoff);
            const unsigned short* bg_ = &Bls[buf][0][((s * 4 + lg) * 32 + l16) * 8];
            const unsigned short* bu_ = &Bls[buf][1][((s * 4 + lg) * 32 + l16) * 8];
            bf16x8 g0 = *(const bf16x8*)(bg_);
            bf16x8 g1 = *(const bf16x8*)(bg_ + 128);
            bf16x8 u0 = *(const bf16x8*)(bu_);
            bf16x8 u1 = *(const bf16x8*)(bu_ + 128);
            accg[0][0] = MFMA16(a0, g0, accg[0][0]);
            accg[0][1] = MFMA16(a0, g1, accg[0][1]);
            accu[0][0] = MFMA16(a0, u0, accu[0][0]);
            accu[0][1] = MFMA16(a0, u1, accu[0][1]);
            accg[1][0] = MFMA16(a1, g0, accg[1][0]);
            accg[1][1] = MFMA16(a1, g1, accg[1][1]);
            accu[1][0] = MFMA16(a1, u0, accu[1][0]);
            accu[1][1] = MFMA16(a1, u1, accu[1][1]);
        }
        if (c + 1 < GU_NC) GU_WRITE((c + 1) & 1);   // write-late (loads done by now)
    }
#undef GU_LOAD
#undef GU_WRITE

    // epilogue: silu(g)*u*wgt -> h_t panels [ic][slot][8]
#pragma unroll
    for (int i = 0; i < 2; ++i) {
        const int mloc = w * 32 + i * 16 + lg * 4;
#pragma unroll
        for (int r = 0; r < 4; ++r) {
            const int mrow = mt * 256 + mloc + r;
            if (mrow < count) {
                const float wgt = wls[mloc + r];
                const size_t slot = (size_t)(base + mrow);
#pragma unroll
                for (int f = 0; f < 2; ++f) {
                    const int col = nt * 32 + f * 16 + l16;
                    float g = accg[i][f][r], u = accu[i][f][r];
                    float sv = g / (1.f + expf(-g));
                    __hip_bfloat16 hb = __float2bfloat16(wgt * u * sv);
                    h_t[((size_t)(col >> 3) * S4 + slot) * 8 + (col & 7)] = *(unsigned short*)&hb;
                }
            }
        }
    }
}

// ---------------- down MFMA -> atomic accumulate into out ----------------
// tile 256(M) x 64(N); A reg-direct from h_t panels; B per-128K chunk.
// grid (32e, 32nt, 8mt).
#define DN_NC (I_DIM / 128)   // 6 chunks
__global__ __launch_bounds__(512, 4) void down_mfma(
    const unsigned short* __restrict__ h_t, const float* __restrict__ down_w,
    const int* __restrict__ cnt, const int* __restrict__ slot_base,
    const int* __restrict__ tok_list, float* __restrict__ out)
{
    const int e  = blockIdx.x;
    const int nt = blockIdx.y;
    const int mt = blockIdx.z;
    const int count = cnt[e];
    if (mt * 256 >= count) return;
    const int tid  = threadIdx.x;
    const int lane = tid & 63;
    const int w    = tid >> 6;
    const int base = slot_base[e];
    const int l16  = lane & 15, lg = lane >> 4;

    __shared__ unsigned short Bls[2][16 * 64 * 8];   // [buf][kc16][n64][8] 32KB
    __shared__ int toks[256];                        // 1KB

    if (tid < 256) {
        int m = mt * 256 + tid; if (m >= count) m = count - 1;
        toks[tid] = tok_list[e * T_TOK + m];
    }

    int m0 = mt * 256 + w * 32 + l16;      if (m0 >= count) m0 = count - 1;
    int m1 = mt * 256 + w * 32 + 16 + l16; if (m1 >= count) m1 = count - 1;
    const unsigned short* a0b = h_t + (size_t)(base + m0) * 8;
    const unsigned short* a1b = h_t + (size_t)(base + m1) * 8;

    const int sub = tid >> 8;
    const int t8  = tid & 255;
    const int kb  = (t8 >> 4) * 2;
    const int n4  = (t8 & 15) * 4;
    const int k8  = kb & 7;
    const int kbh = kb >> 3;
    const float* __restrict__ bbase =
        down_w + ((size_t)e * I_DIM + kb) * H_DIM + nt * 64 + n4;

    float4 sv0[2], sv1[2];

#define DN_LOAD(C) do { _Pragma("unroll") for (int q2 = 0; q2 < 2; ++q2) { \
        const int q = sub + q2 * 2; \
        const float* s_ = bbase + (size_t)((C) * 128 + q * 32) * H_DIM; \
        sv0[q2] = *(const float4*)s_; \
        sv1[q2] = *(const float4*)(s_ + H_DIM); } } while (0)
#define DN_WRITE(BUF) do { _Pragma("unroll") for (int q2 = 0; q2 < 2; ++q2) { \
        const int q = sub + q2 * 2; \
        unsigned short* bw_ = &Bls[BUF][((q * 4 + kbh) * 64) * 8]; \
        float p0[4] = {sv0[q2].x, sv0[q2].y, sv0[q2].z, sv0[q2].w}; \
        float p1[4] = {sv1[q2].x, sv1[q2].y, sv1[q2].z, sv1[q2].w}; \
        _Pragma("unroll") for (int j = 0; j < 4; ++j) \
            *(unsigned*)&bw_[(n4 + j) * 8 + k8] = pk2(p0[j], p1[j]); } } while (0)

    f32x4 acc[2][4];
#pragma unroll
    for (int i = 0; i < 2; ++i)
#pragma unroll
        for (int f = 0; f < 4; ++f) acc[i][f] = {0.f,0.f,0.f,0.f};

    DN_LOAD(0);
    DN_WRITE(0);

    for (int c = 0; c < DN_NC; ++c) {
        const int buf = c & 1;
        __syncthreads();
        if (c + 1 < DN_NC) DN_LOAD(c + 1);
#pragma unroll
        for (int s = 0; s < 4; ++s) {
            const size_t aoff = (size_t)(c * 16 + s * 4 + lg) * (S4 * 8);
            bf16x8 a0 = *(const bf16x8*)(a0b + aoff);
            bf16x8 a1 = *(const bf16x8*)(a1b + aoff);
            const unsigned short* bf_ = &Bls[buf][((s * 4 + lg) * 64 + l16) * 8];
            bf16x8 b0 = *(const bf16x8*)(bf_);
            bf16x8 b1 = *(const bf16x8*)(bf_ + 128);
            bf16x8 b2 = *(const bf16x8*)(bf_ + 256);
            bf16x8 b3 = *(const bf16x8*)(bf_ + 384);
            acc[0][0] = MFMA16(a0, b0, acc[0][0]);
            acc[0][1] = MFMA16(a0, b1, acc[0][1]);
            acc[0][2] = MFMA16(a0, b2, acc[0][2]);
            acc[0][3] = MFMA16(a0, b3, acc[0][3]);
            acc[1][0] = MFMA16(a1, b0, acc[1][0]);
            acc[1][1] = MFMA16(a1, b1, acc[1][1]);
            acc[1][2] = MFMA16(a1, b2, acc[1][2]);
            acc[1][3] = MFMA16(a1, b3, acc[1][3]);
        }
        if (c + 1 < DN_NC) DN_WRITE((c + 1) & 1);
    }
#undef DN_LOAD
#undef DN_WRITE

#pragma unroll
    for (int i = 0; i < 2; ++i) {
        const int mloc = w * 32 + i * 16 + lg * 4;
#pragma unroll
        for (int r = 0; r < 4; ++r) {
            const int mrow = mt * 256 + mloc + r;
            if (mrow < count) {
                const int tok = toks[mloc + r];
#pragma unroll
                for (int f = 0; f < 4; ++f) {
                    const int col = nt * 64 + f * 16 + l16;
                    atomicAdd(&out[(size_t)tok * H_DIM + col], acc[i][f][r]);
                }
            }
        }
    }
}

extern "C" void kernel_launch(void* const* d_in, const int* in_sizes, int n_in,
                              void* d_out, int out_size, void* d_ws, size_t ws_size,
                              hipStream_t stream) {
    const float* x      = (const float*)d_in[0];
    const float* gate_w = (const float*)d_in[1];
    const float* gup_w  = (const float*)d_in[2];
    const float* down_w = (const float*)d_in[3];
    float* out    = (float*)d_out;

    char* wsp = (char*)d_ws;
    int*   cnt       = (int*)(wsp);
    int*   slot_base = (int*)(wsp + 256);
    int*   tok_list  = (int*)(wsp + 4096);
    float* tok_w     = (float*)(wsp + 4096 + (size_t)E_NUM * T_TOK * 4);
    unsigned short* xg_t = (unsigned short*)(wsp + (1u << 20));                          // 33.6 MB
    unsigned short* h_t  = (unsigned short*)(wsp + (1u << 20) + (size_t)S4 * H_DIM * 2); // 12.6 MB

    const int n16 = T_TOK * H_DIM / 4;
    zero_kernel<<<(n16 + 255) / 256, 256, 0, stream>>>((uint4*)out, n16);
    hipMemsetAsync(cnt, 0, 256, stream);

    router_kernel<<<T_TOK, 64, 0, stream>>>(x, gate_w, out + (size_t)T_TOK * H_DIM,
                                            cnt, tok_list, tok_w);
    scan_kernel<<<1, 64, 0, stream>>>(cnt, slot_base);
    gather_kernel<<<dim3(E_NUM, 256), 256, 0, stream>>>(x, cnt, slot_base, tok_list, xg_t);
    gateup_mfma<<<dim3(E_NUM, 24, 8), 512, 0, stream>>>(
        xg_t, gup_w, cnt, slot_base, tok_w, h_t);
    down_mfma<<<dim3(E_NUM, 32, 8), 512, 0, stream>>>(
        h_t, down_w, cnt, slot_base, tok_list, out);
}

// Round 12
// 458.715 us; speedup vs baseline: 1.7707x; 1.0194x over previous
//
#include <hip/hip_runtime.h>
#include <hip/hip_bf16.h>

#define T_TOK 2048
#define H_DIM 2048
#define E_NUM 32
#define I_DIM 768
#define TOPK  4
#define S4    (T_TOK * TOPK)          // 8192 slots

typedef __attribute__((ext_vector_type(8))) short bf16x8;
typedef __attribute__((ext_vector_type(4))) float f32x4;

__device__ __forceinline__ unsigned pk2(float a, float b) {
    __hip_bfloat16 ha = __float2bfloat16(a);
    __hip_bfloat16 hb = __float2bfloat16(b);
    unsigned short ua = *(unsigned short*)&ha;
    unsigned short ub = *(unsigned short*)&hb;
    return (unsigned)ua | ((unsigned)ub << 16);
}

#define MFMA16(a, b, c) __builtin_amdgcn_mfma_f32_16x16x32_bf16(a, b, c, 0, 0, 0)

// ---------------- Router ----------------
__global__ __launch_bounds__(64) void router_kernel(
    const float* __restrict__ x, const float* __restrict__ gate_w,
    float* __restrict__ logits_out, int* __restrict__ cnt,
    int* __restrict__ tok_list, float* __restrict__ tok_w,
    int* __restrict__ tok_slots)
{
    const int t = blockIdx.x;
    const int lane = threadIdx.x;
    __shared__ float xs[H_DIM];
    const float4* __restrict__ xv = (const float4*)(x + (size_t)t * H_DIM);
    float4* xsv = (float4*)xs;
#pragma unroll
    for (int i = 0; i < H_DIM / 4 / 64; ++i) xsv[lane + i * 64] = xv[lane + i * 64];
    __syncthreads();

    const int e = lane & 31;
    const int half = lane >> 5;
    const float4* __restrict__ wv = (const float4*)(gate_w + (size_t)e * H_DIM) + half * (H_DIM / 8);
    const float4* __restrict__ xh = ((const float4*)xs) + half * (H_DIM / 8);
    float acc = 0.f;
#pragma unroll 4
    for (int i = 0; i < H_DIM / 8; ++i) {
        float4 w4 = wv[i], x4 = xh[i];
        acc += w4.x * x4.x + w4.y * x4.y + w4.z * x4.z + w4.w * x4.w;
    }
    acc += __shfl_xor(acc, 32, 64);
    if (lane < 32) logits_out[(size_t)t * E_NUM + e] = acc;

    float v = acc;
    float topv[TOPK]; int topi[TOPK];
#pragma unroll
    for (int r = 0; r < TOPK; ++r) {
        float bv = v; int bi = e;
#pragma unroll
        for (int off = 16; off >= 1; off >>= 1) {
            float ov = __shfl_xor(bv, off, 32);
            int   oi = __shfl_xor(bi, off, 32);
            if (ov > bv || (ov == bv && oi < bi)) { bv = ov; bi = oi; }
        }
        topv[r] = bv; topi[r] = bi;
        if (e == bi) v = -1e30f;
    }
    if (lane == 0) {
        float w[TOPK]; float s = 0.f;
#pragma unroll
        for (int r = 0; r < TOPK; ++r) { w[r] = expf(topv[r] - topv[0]); s += w[r]; }
        float inv = 1.f / s;
#pragma unroll
        for (int r = 0; r < TOPK; ++r) {
            int pos = atomicAdd(&cnt[topi[r]], 1);
            tok_list[topi[r] * T_TOK + pos] = t;
            tok_w  [topi[r] * T_TOK + pos] = w[r] * inv;
            tok_slots[t * TOPK + r] = (topi[r] << 12) | pos;
        }
    }
}

__global__ void scan_kernel(const int* __restrict__ cnt, int* __restrict__ slot_base)
{
    if (threadIdx.x == 0) {
        int s = 0;
        for (int e = 0; e < E_NUM; ++e) { slot_base[e] = s; s += cnt[e]; }
        slot_base[E_NUM] = s;
    }
}

// ------- Gather tokens per expert, convert x -> bf16 in K-PANEL layout -------
__global__ __launch_bounds__(256) void gather_kernel(
    const float* __restrict__ x, const int* __restrict__ cnt,
    const int* __restrict__ slot_base, const int* __restrict__ tok_list,
    unsigned short* __restrict__ xg_t)
{
    const int e = blockIdx.x;
    const int count = cnt[e];
    const int m0 = blockIdx.y * 8;
    if (m0 >= count) return;
    const int s8   = threadIdx.x >> 5;
    const int kc31 = threadIdx.x & 31;
    const int m = m0 + s8;
    if (m >= count) return;
    const int tok  = tok_list[e * T_TOK + m];
    const int slot = slot_base[e] + m;
    const float* __restrict__ src = x + (size_t)tok * H_DIM;
#pragma unroll
    for (int kcq = 0; kcq < 8; ++kcq) {
        const int kc = kcq * 32 + kc31;
        float4 a = *(const float4*)(src + kc * 8);
        float4 b = *(const float4*)(src + kc * 8 + 4);
        uint4 o;
        o.x = pk2(a.x, a.y); o.y = pk2(a.z, a.w);
        o.z = pk2(b.x, b.y); o.w = pk2(b.z, b.w);
        *(uint4*)(xg_t + ((size_t)kc * S4 + slot) * 8) = o;
    }
}

// ---------------- gate_up MFMA + silu + weight-scale -> h_t (panel bf16) -----
// tile 256(M) x 32(g)+32(u); A reg-direct from panels; B per-128K chunk.
#define GU_NC (H_DIM / 128)   // 16 chunks
__global__ __launch_bounds__(512, 4) void gateup_mfma(
    const unsigned short* __restrict__ xg_t, const float* __restrict__ gup_w,
    const int* __restrict__ cnt, const int* __restrict__ slot_base,
    const float* __restrict__ tok_w, unsigned short* __restrict__ h_t)
{
    const int e  = blockIdx.x;
    const int nt = blockIdx.y;
    const int mt = blockIdx.z;
    const int count = cnt[e];
    if (mt * 256 >= count) return;
    const int tid  = threadIdx.x;
    const int lane = tid & 63;
    const int w    = tid >> 6;
    const int base = slot_base[e];
    const int l16  = lane & 15, lg = lane >> 4;

    __shared__ unsigned short Bls[2][2][16 * 32 * 8];  // [buf][half][kc16][n32][8] 32KB
    __shared__ float wls[256];                         // 1KB

    if (tid < 256) {
        int m = mt * 256 + tid; if (m >= count) m = count - 1;
        wls[tid] = tok_w[e * T_TOK + m];
    }

    int m0 = mt * 256 + w * 32 + l16;      if (m0 >= count) m0 = count - 1;
    int m1 = mt * 256 + w * 32 + 16 + l16; if (m1 >= count) m1 = count - 1;
    const unsigned short* a0b = xg_t + (size_t)(base + m0) * 8;
    const unsigned short* a1b = xg_t + (size_t)(base + m1) * 8;

    const int bhalf = tid >> 8;
    const int sub   = (tid >> 7) & 1;
    const int t7    = tid & 127;
    const int kb    = (t7 >> 3) * 2;
    const int n4    = (t7 & 7) * 4;
    const int k8    = kb & 7;
    const int kbh   = kb >> 3;
    const float* __restrict__ bbase =
        gup_w + ((size_t)e * H_DIM + kb) * (2 * I_DIM) + (size_t)bhalf * I_DIM + nt * 32 + n4;

    float4 sv0[2], sv1[2];

#define GU_LOAD(C) do { _Pragma("unroll") for (int q2 = 0; q2 < 2; ++q2) { \
        const int q = sub + q2 * 2; \
        const float* s_ = bbase + (size_t)((C) * 128 + q * 32) * (2 * I_DIM); \
        sv0[q2] = *(const float4*)s_; \
        sv1[q2] = *(const float4*)(s_ + 2 * I_DIM); } } while (0)
#define GU_WRITE(BUF) do { _Pragma("unroll") for (int q2 = 0; q2 < 2; ++q2) { \
        const int q = sub + q2 * 2; \
        unsigned short* bw_ = &Bls[BUF][bhalf][((q * 4 + kbh) * 32) * 8]; \
        float p0[4] = {sv0[q2].x, sv0[q2].y, sv0[q2].z, sv0[q2].w}; \
        float p1[4] = {sv1[q2].x, sv1[q2].y, sv1[q2].z, sv1[q2].w}; \
        _Pragma("unroll") for (int j = 0; j < 4; ++j) \
            *(unsigned*)&bw_[(n4 + j) * 8 + k8] = pk2(p0[j], p1[j]); } } while (0)

    f32x4 accg[2][2], accu[2][2];
#pragma unroll
    for (int i = 0; i < 2; ++i)
#pragma unroll
        for (int f = 0; f < 2; ++f) { accg[i][f] = {0.f,0.f,0.f,0.f}; accu[i][f] = {0.f,0.f,0.f,0.f}; }

    GU_LOAD(0);
    GU_WRITE(0);

    for (int c = 0; c < GU_NC; ++c) {
        const int buf = c & 1;
        __syncthreads();
        if (c + 1 < GU_NC) GU_LOAD(c + 1);
#pragma unroll
        for (int s = 0; s < 4; ++s) {
            const size_t aoff = (size_t)(c * 16 + s * 4 + lg) * (S4 * 8);
            bf16x8 a0 = *(const bf16x8*)(a0b + aoff);
            bf16x8 a1 = *(const bf16x8*)(a1b + aoff);
            const unsigned short* bg_ = &Bls[buf][0][((s * 4 + lg) * 32 + l16) * 8];
            const unsigned short* bu_ = &Bls[buf][1][((s * 4 + lg) * 32 + l16) * 8];
            bf16x8 g0 = *(const bf16x8*)(bg_);
            bf16x8 g1 = *(const bf16x8*)(bg_ + 128);
            bf16x8 u0 = *(const bf16x8*)(bu_);
            bf16x8 u1 = *(const bf16x8*)(bu_ + 128);
            accg[0][0] = MFMA16(a0, g0, accg[0][0]);
            accg[0][1] = MFMA16(a0, g1, accg[0][1]);
            accu[0][0] = MFMA16(a0, u0, accu[0][0]);
            accu[0][1] = MFMA16(a0, u1, accu[0][1]);
            accg[1][0] = MFMA16(a1, g0, accg[1][0]);
            accg[1][1] = MFMA16(a1, g1, accg[1][1]);
            accu[1][0] = MFMA16(a1, u0, accu[1][0]);
            accu[1][1] = MFMA16(a1, u1, accu[1][1]);
        }
        if (c + 1 < GU_NC) GU_WRITE((c + 1) & 1);
    }
#undef GU_LOAD
#undef GU_WRITE

#pragma unroll
    for (int i = 0; i < 2; ++i) {
        const int mloc = w * 32 + i * 16 + lg * 4;
#pragma unroll
        for (int r = 0; r < 4; ++r) {
            const int mrow = mt * 256 + mloc + r;
            if (mrow < count) {
                const float wgt = wls[mloc + r];
                const size_t slot = (size_t)(base + mrow);
#pragma unroll
                for (int f = 0; f < 2; ++f) {
                    const int col = nt * 32 + f * 16 + l16;
                    float g = accg[i][f][r], u = accu[i][f][r];
                    float sv = g / (1.f + expf(-g));
                    __hip_bfloat16 hb = __float2bfloat16(wgt * u * sv);
                    h_t[((size_t)(col >> 3) * S4 + slot) * 8 + (col & 7)] = *(unsigned short*)&hb;
                }
            }
        }
    }
}

// ---------------- down MFMA -> slot-major f32 rows (NO atomics) ----------------
// tile 256(M) x 64(N); A reg-direct from h_t panels; B per-128K chunk.
#define DN_NC (I_DIM / 128)   // 6 chunks
__global__ __launch_bounds__(512, 4) void down_mfma(
    const unsigned short* __restrict__ h_t, const float* __restrict__ down_w,
    const int* __restrict__ cnt, const int* __restrict__ slot_base,
    float* __restrict__ ods)
{
    const int e  = blockIdx.x;
    const int nt = blockIdx.y;
    const int mt = blockIdx.z;
    const int count = cnt[e];
    if (mt * 256 >= count) return;
    const int tid  = threadIdx.x;
    const int lane = tid & 63;
    const int w    = tid >> 6;
    const int base = slot_base[e];
    const int l16  = lane & 15, lg = lane >> 4;

    __shared__ unsigned short Bls[2][16 * 64 * 8];   // [buf][kc16][n64][8] 32KB

    int m0 = mt * 256 + w * 32 + l16;      if (m0 >= count) m0 = count - 1;
    int m1 = mt * 256 + w * 32 + 16 + l16; if (m1 >= count) m1 = count - 1;
    const unsigned short* a0b = h_t + (size_t)(base + m0) * 8;
    const unsigned short* a1b = h_t + (size_t)(base + m1) * 8;

    const int sub = tid >> 8;
    const int t8  = tid & 255;
    const int kb  = (t8 >> 4) * 2;
    const int n4  = (t8 & 15) * 4;
    const int k8  = kb & 7;
    const int kbh = kb >> 3;
    const float* __restrict__ bbase =
        down_w + ((size_t)e * I_DIM + kb) * H_DIM + nt * 64 + n4;

    float4 sv0[2], sv1[2];

#define DN_LOAD(C) do { _Pragma("unroll") for (int q2 = 0; q2 < 2; ++q2) { \
        const int q = sub + q2 * 2; \
        const float* s_ = bbase + (size_t)((C) * 128 + q * 32) * H_DIM; \
        sv0[q2] = *(const float4*)s_; \
        sv1[q2] = *(const float4*)(s_ + H_DIM); } } while (0)
#define DN_WRITE(BUF) do { _Pragma("unroll") for (int q2 = 0; q2 < 2; ++q2) { \
        const int q = sub + q2 * 2; \
        unsigned short* bw_ = &Bls[BUF][((q * 4 + kbh) * 64) * 8]; \
        float p0[4] = {sv0[q2].x, sv0[q2].y, sv0[q2].z, sv0[q2].w}; \
        float p1[4] = {sv1[q2].x, sv1[q2].y, sv1[q2].z, sv1[q2].w}; \
        _Pragma("unroll") for (int j = 0; j < 4; ++j) \
            *(unsigned*)&bw_[(n4 + j) * 8 + k8] = pk2(p0[j], p1[j]); } } while (0)

    f32x4 acc[2][4];
#pragma unroll
    for (int i = 0; i < 2; ++i)
#pragma unroll
        for (int f = 0; f < 4; ++f) acc[i][f] = {0.f,0.f,0.f,0.f};

    DN_LOAD(0);
    DN_WRITE(0);

    for (int c = 0; c < DN_NC; ++c) {
        const int buf = c & 1;
        __syncthreads();
        if (c + 1 < DN_NC) DN_LOAD(c + 1);
#pragma unroll
        for (int s = 0; s < 4; ++s) {
            const size_t aoff = (size_t)(c * 16 + s * 4 + lg) * (S4 * 8);
            bf16x8 a0 = *(const bf16x8*)(a0b + aoff);
            bf16x8 a1 = *(const bf16x8*)(a1b + aoff);
            const unsigned short* bf_ = &Bls[buf][((s * 4 + lg) * 64 + l16) * 8];
            bf16x8 b0 = *(const bf16x8*)(bf_);
            bf16x8 b1 = *(const bf16x8*)(bf_ + 128);
            bf16x8 b2 = *(const bf16x8*)(bf_ + 256);
            bf16x8 b3 = *(const bf16x8*)(bf_ + 384);
            acc[0][0] = MFMA16(a0, b0, acc[0][0]);
            acc[0][1] = MFMA16(a0, b1, acc[0][1]);
            acc[0][2] = MFMA16(a0, b2, acc[0][2]);
            acc[0][3] = MFMA16(a0, b3, acc[0][3]);
            acc[1][0] = MFMA16(a1, b0, acc[1][0]);
            acc[1][1] = MFMA16(a1, b1, acc[1][1]);
            acc[1][2] = MFMA16(a1, b2, acc[1][2]);
            acc[1][3] = MFMA16(a1, b3, acc[1][3]);
        }
        if (c + 1 < DN_NC) DN_WRITE((c + 1) & 1);
    }
#undef DN_LOAD
#undef DN_WRITE

    // epilogue: plain coalesced f32 stores into slot-major ods
#pragma unroll
    for (int i = 0; i < 2; ++i) {
        const int mloc = w * 32 + i * 16 + lg * 4;
#pragma unroll
        for (int r = 0; r < 4; ++r) {
            const int mrow = mt * 256 + mloc + r;
            if (mrow < count) {
                float* orow = ods + (size_t)(base + mrow) * H_DIM + nt * 64;
#pragma unroll
                for (int f = 0; f < 4; ++f)
                    orow[f * 16 + l16] = acc[i][f][r];
            }
        }
    }
}

// ---------------- combine: out[t] = sum of t's 4 slot rows ----------------
__global__ __launch_bounds__(256) void combine_kernel(
    const float* __restrict__ ods, const int* __restrict__ tok_slots,
    const int* __restrict__ slot_base, float* __restrict__ out)
{
    const int t = blockIdx.x;
    const int c0 = threadIdx.x * 8;
    const float* rows[TOPK];
#pragma unroll
    for (int r = 0; r < TOPK; ++r) {
        const int pk = tok_slots[t * TOPK + r];
        const int e = pk >> 12, pos = pk & 4095;
        rows[r] = ods + (size_t)(slot_base[e] + pos) * H_DIM + c0;
    }
    float4 a0 = {0.f,0.f,0.f,0.f}, a1 = {0.f,0.f,0.f,0.f};
#pragma unroll
    for (int r = 0; r < TOPK; ++r) {
        float4 v0 = *(const float4*)(rows[r]);
        float4 v1 = *(const float4*)(rows[r] + 4);
        a0.x += v0.x; a0.y += v0.y; a0.z += v0.z; a0.w += v0.w;
        a1.x += v1.x; a1.y += v1.y; a1.z += v1.z; a1.w += v1.w;
    }
    float* o = out + (size_t)t * H_DIM + c0;
    *(float4*)o = a0;
    *(float4*)(o + 4) = a1;
}

extern "C" void kernel_launch(void* const* d_in, const int* in_sizes, int n_in,
                              void* d_out, int out_size, void* d_ws, size_t ws_size,
                              hipStream_t stream) {
    const float* x      = (const float*)d_in[0];
    const float* gate_w = (const float*)d_in[1];
    const float* gup_w  = (const float*)d_in[2];
    const float* down_w = (const float*)d_in[3];
    float* out    = (float*)d_out;

    char* wsp = (char*)d_ws;
    int*   cnt       = (int*)(wsp);
    int*   slot_base = (int*)(wsp + 256);
    int*   tok_list  = (int*)(wsp + 4096);
    float* tok_w     = (float*)(wsp + 4096 + (size_t)E_NUM * T_TOK * 4);
    int*   tok_slots = (int*)(wsp + (768u << 10));                                       // 32 KB
    unsigned short* xg_t = (unsigned short*)(wsp + (1u << 20));                          // 33.6 MB
    unsigned short* h_t  = (unsigned short*)(wsp + (1u << 20) + (size_t)S4 * H_DIM * 2); // 12.6 MB
    float* ods = (float*)(wsp + (1u << 20) + (size_t)S4 * H_DIM * 2 + (size_t)S4 * I_DIM * 2); // 67 MB

    hipMemsetAsync(cnt, 0, 256, stream);

    router_kernel<<<T_TOK, 64, 0, stream>>>(x, gate_w, out + (size_t)T_TOK * H_DIM,
                                            cnt, tok_list, tok_w, tok_slots);
    scan_kernel<<<1, 64, 0, stream>>>(cnt, slot_base);
    gather_kernel<<<dim3(E_NUM, 256), 256, 0, stream>>>(x, cnt, slot_base, tok_list, xg_t);
    gateup_mfma<<<dim3(E_NUM, 24, 8), 512, 0, stream>>>(
        xg_t, gup_w, cnt, slot_base, tok_w, h_t);
    down_mfma<<<dim3(E_NUM, 32, 8), 512, 0, stream>>>(
        h_t, down_w, cnt, slot_base, ods);
    combine_kernel<<<T_TOK, 256, 0, stream>>>(ods, tok_slots, slot_base, out);
}